// Round 5
// baseline (179.409 us; speedup 1.0000x reference)
//
#include <hip/hip_runtime.h>
#include <hip/hip_bf16.h>
#include <math.h>

typedef __attribute__((ext_vector_type(8))) short bf16x8;
typedef __attribute__((ext_vector_type(4))) float f32x4;

#define NBAG 128
#define MM 16
#define LL 120
#define WEMB 50
#define PEMB 5
#define OC 230
#define RR 53
#define DD 60

#define XPAD 72        // bf16 row stride for x tile (144 B)
#define XROWS 132      // rows -2..121 stored at +2, zero tail to 131
#define FSTRIDE 280    // feat16 row stride (560 B)
#define KP2 256        // scores-GEMM K (230 padded)

#define PREPB 12       // prep blocks
#define QB 212         // 53 r x 4 c-quarters
#define PACK2B 8       // pack2 blocks

static __device__ __forceinline__ short f2bf(float v) {
    __hip_bfloat16 b = __float2bfloat16(v);
    return *reinterpret_cast<short*>(&b);
}

static __device__ __forceinline__ void gload_lds16(const void* g, void* l) {
    __builtin_amdgcn_global_load_lds(
        (const __attribute__((address_space(1))) void*)g,
        (__attribute__((address_space(3))) void*)l, 16, 0, 0);
}

// ================= kernel A: prep (12) | q partials (212) =================
__global__ __launch_bounds__(512) void kernelA(
    const float* __restrict__ cw, const float* __restrict__ attW,
    const float* __restrict__ re,
    __hip_bfloat16* __restrict__ wsB, float* __restrict__ qf)
{
    __shared__ float part[2][256];
    int tid = threadIdx.x;
    int bid = blockIdx.x;

    if (bid < PREPB) {
        // ---- prep: conv weights -> bf16 MFMA-fragment order ----
        int t = bid * 512 + tid;
        if (t >= 4 * 6 * 4 * 64) return;
        int lane = t & 63, frag = t >> 6;
        int nt = frag & 3, rem = frag >> 2;
        int ks = rem % 6, oq = rem / 6;
        int oc = oq * 64 + nt * 16 + (lane & 15);
        int k0 = ks * 32 + (lane >> 4) * 8;
        bf16x8 o;
        #pragma unroll
        for (int e = 0; e < 8; ++e) {
            int k = k0 + e, kh = k >> 6, d = k & 63;
            float v = (oc < OC && d < DD) ? cw[oc * (3 * DD) + kh * DD + d] : 0.f;
            o[e] = f2bf(v);
        }
        ((bf16x8*)wsB)[t] = o;
        return;
    }

    // ---- q partial: qf[qt][r][d] = sum_{c in quarter} re[r][c]*attW[r][c][d] ----
    int qb = bid - PREPB;
    int r = qb >> 2, qt = qb & 3;
    int cs = tid >> 8, d = tid & 255;
    int c0 = qt * 58 + cs * 29;
    int c1 = min(OC, qt * 58 + (cs + 1) * 29);
    const float* W = attW + (size_t)r * OC * OC;
    const float* rer = re + r * OC;
    float acc = 0.f;
    if (d < OC)
        for (int c = c0; c < c1; ++c) acc += rer[c] * W[(size_t)c * OC + d];
    part[cs][d] = acc;
    __syncthreads();
    if (cs == 0 && d < OC)
        qf[qt * (RR * OC) + r * OC + d] = part[0][d] + part[1][d];
}

// ================= kernel B: pack2 (8) | fused gather+conv (2048) =================
__global__ __launch_bounds__(512, 6) void kernelB(
    const int* __restrict__ wid, const int* __restrict__ p1, const int* __restrict__ p2,
    const float* __restrict__ w2v, const float* __restrict__ pemb,
    const __hip_bfloat16* __restrict__ wsB, const float* __restrict__ cb,
    const float* __restrict__ qf, const float* __restrict__ re,
    __hip_bfloat16* __restrict__ wsB2, __hip_bfloat16* __restrict__ feat16)
{
    __shared__ __hip_bfloat16 xs[XROWS * XPAD];   // 19,008 B
    __shared__ float sm[2][256];                  //  2,048 B
    int tid = threadIdx.x;
    int bid = blockIdx.x;

    if (bid < PACK2B) {
        // ---- pack2: B2[256][128] frags: cols 0..52 = q rows, 64..116 = re rows ----
        int t = bid * 512 + tid;
        int lane = t & 63, f = t >> 6;
        int ks = f >> 3, nt = f & 7;
        int col = nt * 16 + (lane & 15);
        int k0 = ks * 32 + (lane >> 4) * 8;
        bf16x8 o;
        #pragma unroll
        for (int e = 0; e < 8; ++e) {
            int k = k0 + e;
            float v = 0.f;
            if (k < OC) {
                if (col < RR)
                    v = qf[col * OC + k] + qf[RR * OC + col * OC + k]
                      + qf[2 * RR * OC + col * OC + k] + qf[3 * RR * OC + col * OC + k];
                else if (col >= 64 && col < 64 + RR)
                    v = re[(col - 64) * OC + k];
            }
            o[e] = f2bf(v);
        }
        ((bf16x8*)wsB2)[t] = o;
        return;
    }

    // ---- fused gather into LDS: 132 rows x 9 chunks of 8 cols ----
    int sid = bid - PACK2B;
    const int base = sid * LL;
    for (int t = tid; t < XROWS * 9; t += 512) {
        int row = t / 9, c = t - row * 9;
        bf16x8 o = (bf16x8){0,0,0,0,0,0,0,0};
        if (row >= 2 && row < 122 && c < 8) {
            int b2 = base + (row - 2);
            if (c < 6) {                     // cols 0..47: pure w2v
                const float2* p = (const float2*)(w2v + (size_t)wid[b2] * WEMB + c * 8);
                float2 x0 = p[0], x1 = p[1], x2 = p[2], x3 = p[3];
                o[0] = f2bf(x0.x); o[1] = f2bf(x0.y);
                o[2] = f2bf(x1.x); o[3] = f2bf(x1.y);
                o[4] = f2bf(x2.x); o[5] = f2bf(x2.y);
                o[6] = f2bf(x3.x); o[7] = f2bf(x3.y);
            } else if (c == 6) {             // cols 48,49 w2v | 50..54 p1 | 55 p2
                float2 x0 = *(const float2*)(w2v + (size_t)wid[b2] * WEMB + 48);
                const float* e1 = pemb + p1[b2] * PEMB;
                const float* e2 = pemb + p2[b2] * PEMB;
                o[0] = f2bf(x0.x); o[1] = f2bf(x0.y);
                o[2] = f2bf(e1[0]); o[3] = f2bf(e1[1]); o[4] = f2bf(e1[2]);
                o[5] = f2bf(e1[3]); o[6] = f2bf(e1[4]);
                o[7] = f2bf(e2[0]);
            } else {                         // c==7: cols 56..59 = p2[1..4], 60..63 zero
                const float* e2 = pemb + p2[b2] * PEMB;
                o[0] = f2bf(e2[1]); o[1] = f2bf(e2[2]);
                o[2] = f2bf(e2[3]); o[3] = f2bf(e2[4]);
            }
        }
        *(bf16x8*)&xs[row * XPAD + c * 8] = o;
    }
    __syncthreads();

    // ---- conv GEMM + maxpool + bias + tanh -> feat bf16 ----
    int lane = tid & 63, wave = tid >> 6;
    int oq = wave >> 1, th = wave & 1;
    int lr = lane & 15, lh = lane >> 4;

    f32x4 acc[4][4];
    #pragma unroll
    for (int a = 0; a < 4; ++a)
        #pragma unroll
        for (int b = 0; b < 4; ++b) acc[a][b] = (f32x4){0.f, 0.f, 0.f, 0.f};

    const bf16x8* wb = (const bf16x8*)wsB;
    #pragma unroll
    for (int ks = 0; ks < 6; ++ks) {
        bf16x8 bfrag[4];
        #pragma unroll
        for (int nt = 0; nt < 4; ++nt)
            bfrag[nt] = wb[((oq * 6 + ks) * 4 + nt) * 64 + lane];
        int k = ks * 32 + lh * 8;
        int kh = k >> 6, d = k & 63;
        #pragma unroll
        for (int mt = 0; mt < 4; ++mt) {
            int xrow = th * 64 + mt * 16 + lr + kh;
            bf16x8 af = *(const bf16x8*)&xs[xrow * XPAD + d];
            #pragma unroll
            for (int nt = 0; nt < 4; ++nt)
                acc[mt][nt] = __builtin_amdgcn_mfma_f32_16x16x32_bf16(af, bfrag[nt], acc[mt][nt], 0, 0, 0);
        }
    }

    #pragma unroll
    for (int nt = 0; nt < 4; ++nt) {
        float mx = -1e30f;
        #pragma unroll
        for (int mt = 0; mt < 4; ++mt) {
            #pragma unroll
            for (int r = 0; r < 4; ++r) {
                int t = th * 64 + mt * 16 + lh * 4 + r;
                if (t < 122) mx = fmaxf(mx, acc[mt][nt][r]);
            }
        }
        mx = fmaxf(mx, __shfl_xor(mx, 16));
        mx = fmaxf(mx, __shfl_xor(mx, 32));
        if (lane < 16) sm[th][oq * 64 + nt * 16 + lr] = mx;
    }
    __syncthreads();
    if (tid < KP2) {
        float v = (tid < OC) ? tanhf(fmaxf(sm[0][tid], sm[1][tid]) + cb[tid]) : 0.f;
        feat16[(size_t)sid * FSTRIDE + tid] = __float2bfloat16(v);
    }
}

// ================= kernel C: per-bag attention + logits + log-softmax + max =================
__global__ __launch_bounds__(512) void bag_kernel(
    const __hip_bfloat16* __restrict__ feat16, const __hip_bfloat16* __restrict__ wsB2,
    const float* __restrict__ rb, float* __restrict__ out)
{
    __shared__ __hip_bfloat16 fA[MM * FSTRIDE];
    __shared__ float scg[MM][132];
    __shared__ float att[RR][17];
    __shared__ float lg[RR * 56];
    __shared__ float lse[RR];
    int b = blockIdx.x, tid = threadIdx.x;
    int lane = tid & 63, wave = tid >> 6;
    int lr = lane & 15, lh = lane >> 4;

    const char* gf = (const char*)(feat16 + (size_t)b * MM * FSTRIDE);
    char* lf = (char*)fA;
    #pragma unroll
    for (int i = 0; i < 2; ++i) {
        int off = i * 8192 + wave * 1024 + lane * 16;
        if (off < MM * FSTRIDE * 2) gload_lds16(gf + off, lf + i * 8192 + wave * 1024);
    }
    __syncthreads();

    f32x4 acc = (f32x4){0.f, 0.f, 0.f, 0.f};
    const bf16x8* wb2 = (const bf16x8*)wsB2;
    #pragma unroll
    for (int ks = 0; ks < 8; ++ks) {
        bf16x8 bfrag = wb2[(ks * 8 + wave) * 64 + lane];
        int k = ks * 32 + lh * 8;
        bf16x8 af = *(const bf16x8*)((const char*)fA + lr * (FSTRIDE * 2) + k * 2);
        acc = __builtin_amdgcn_mfma_f32_16x16x32_bf16(af, bfrag, acc, 0, 0, 0);
    }
    #pragma unroll
    for (int r = 0; r < 4; ++r) scg[lh * 4 + r][wave * 16 + lr] = acc[r];
    __syncthreads();

    if (tid < RR) {
        float mx = -1e30f;
        #pragma unroll
        for (int m = 0; m < MM; ++m) mx = fmaxf(mx, scg[m][tid]);
        float s = 0.f, e[MM];
        #pragma unroll
        for (int m = 0; m < MM; ++m) { e[m] = expf(scg[m][tid] - mx); s += e[m]; }
        float inv = 1.f / s;
        #pragma unroll
        for (int m = 0; m < MM; ++m) att[tid][m] = e[m] * inv;
    }
    __syncthreads();

    for (int idx = tid; idx < RR * RR; idx += 512) {
        int r = idx % RR, s2 = idx / RR;
        float a = 0.f;
        #pragma unroll
        for (int m = 0; m < MM; ++m) a += att[r][m] * scg[m][64 + s2];
        lg[r * 56 + s2] = 0.5f * a + rb[s2];
    }
    __syncthreads();

    if (tid < RR) {
        float mx = -1e30f;
        for (int s2 = 0; s2 < RR; ++s2) mx = fmaxf(mx, lg[tid * 56 + s2]);
        float s = 0.f;
        for (int s2 = 0; s2 < RR; ++s2) s += expf(lg[tid * 56 + s2] - mx);
        lse[tid] = mx + logf(s);
    }
    __syncthreads();

    if (tid < RR) {
        float mx = -1e30f;
        for (int r = 0; r < RR; ++r) mx = fmaxf(mx, lg[r * 56 + tid] - lse[r]);
        out[b * RR + tid] = mx;
    }
}

extern "C" void kernel_launch(void* const* d_in, const int* in_sizes, int n_in,
                              void* d_out, int out_size, void* d_ws, size_t ws_size,
                              hipStream_t stream) {
    const int* wid   = (const int*)d_in[0];
    const int* p1    = (const int*)d_in[1];
    const int* p2    = (const int*)d_in[2];
    const float* w2v = (const float*)d_in[3];
    const float* pe  = (const float*)d_in[4];
    const float* cw  = (const float*)d_in[5];
    const float* cb  = (const float*)d_in[6];
    const float* re  = (const float*)d_in[7];
    const float* rb  = (const float*)d_in[8];
    const float* attW= (const float*)d_in[9];
    float* out = (float*)d_out;

    // ws layout
    float* qf            = (float*)d_ws;                                 // 4*53*230*4 = 195,040
    __hip_bfloat16* wsB  = (__hip_bfloat16*)((char*)d_ws + 196608);      // 98,304
    __hip_bfloat16* wsB2 = (__hip_bfloat16*)((char*)d_ws + 294912);      // 65,536
    __hip_bfloat16* f16  = (__hip_bfloat16*)((char*)d_ws + 360448);      // 2048*280*2 = 1,146,880

    kernelA<<<PREPB + QB, 512, 0, stream>>>(cw, attW, re, wsB, qf);
    kernelB<<<PACK2B + NBAG * MM, 512, 0, stream>>>(wid, p1, p2, w2v, pe,
                                                    wsB, cb, qf, re, wsB2, f16);
    bag_kernel<<<NBAG, 512, 0, stream>>>(f16, wsB2, rb, out);
}